// Round 1
// baseline (2226.752 us; speedup 1.0000x reference)
//
#include <hip/hip_runtime.h>

#define N_NODES 8192
#define IN_DIM  512
#define HID     256
#define LAT     128
#define NEDGE   262144

typedef __attribute__((ext_vector_type(8))) short  bf16x8;
typedef __attribute__((ext_vector_type(4))) float  f32x4;
typedef unsigned short u16;

// ---- bf16 helpers (manual, RNE) ----
static __device__ inline u16 f2bf(float f) {
    unsigned u = __float_as_uint(f);
    unsigned r = (u + 0x7fffu + ((u >> 16) & 1u)) >> 16;
    return (u16)r;
}
static __device__ inline float bf2f(u16 s) {
    return __uint_as_float(((unsigned)s) << 16);
}

// ---- degree via atomics (self-loop added in dinv pass) ----
__global__ __launch_bounds__(256) void deg_kernel(const int* __restrict__ dst,
                                                  float* __restrict__ deg) {
    int e = blockIdx.x * 256 + threadIdx.x;
    atomicAdd(&deg[dst[e]], 1.0f);
}

__global__ __launch_bounds__(256) void dinv_kernel(float* __restrict__ deg) {
    int v = blockIdx.x * 256 + threadIdx.x;
    deg[v] = rsqrtf(deg[v] + 1.0f);   // +1 self-loop; always > 0
}

// ---- fp32 tiled GEMM: C[., coff + colBase...] = A[M,K] @ B[K,ldb] ----
// 64x64 tile, BK=16, 256 threads, 4x4 per thread.
__global__ __launch_bounds__(256) void gemm_f32(const float* __restrict__ A,
                                                const float* __restrict__ B,
                                                float* __restrict__ C,
                                                int Ktot, int ldb, int ldc, int coff) {
    __shared__ float As[16][68];   // A^T tile, padded
    __shared__ float Bs[16][64];
    const int tid = threadIdx.x;
    const int tx = tid & 15, ty = tid >> 4;
    const int rowBase = blockIdx.y * 64, colBase = blockIdx.x * 64;

    float acc[4][4] = {};
    const int am = rowBase + (tid >> 2);
    const int ak = (tid & 3) * 4;
    const int bk = tid >> 4;
    const int bn = colBase + (tid & 15) * 4;

    for (int k0 = 0; k0 < Ktot; k0 += 16) {
        f32x4 av = *(const f32x4*)(A + (size_t)am * Ktot + k0 + ak);
        f32x4 bv = *(const f32x4*)(B + (size_t)(k0 + bk) * ldb + bn);
#pragma unroll
        for (int j = 0; j < 4; ++j) As[ak + j][tid >> 2] = av[j];
        *(f32x4*)&Bs[bk][(tid & 15) * 4] = bv;
        __syncthreads();
#pragma unroll
        for (int kk = 0; kk < 16; ++kk) {
            f32x4 a = *(const f32x4*)&As[kk][ty * 4];
            f32x4 b = *(const f32x4*)&Bs[kk][tx * 4];
#pragma unroll
            for (int i = 0; i < 4; ++i)
#pragma unroll
                for (int j = 0; j < 4; ++j)
                    acc[i][j] += a[i] * b[j];
        }
        __syncthreads();
    }
#pragma unroll
    for (int i = 0; i < 4; ++i) {
        int r = rowBase + ty * 4 + i;
        f32x4 v = { acc[i][0], acc[i][1], acc[i][2], acc[i][3] };
        *(f32x4*)(C + (size_t)r * ldc + coff + colBase + tx * 4) = v;
    }
}

// ---- edge aggregation: acc[dst] += dinv[s]*dinv[d] * H[src], 256-wide rows ----
// one wave (64 lanes) per edge, float4 per lane
__global__ __launch_bounds__(256) void agg_kernel(const float* __restrict__ H,
                                                  float* __restrict__ acc,
                                                  const int* __restrict__ src,
                                                  const int* __restrict__ dst,
                                                  const float* __restrict__ dinv) {
    int wave = threadIdx.x >> 6, lane = threadIdx.x & 63;
    int e = blockIdx.x * 4 + wave;
    int s = src[e], d = dst[e];
    float nrm = dinv[s] * dinv[d];
    f32x4 v = *(const f32x4*)(H + (size_t)s * HID + lane * 4);
    float* p = acc + (size_t)d * HID + lane * 4;
    atomicAdd(p + 0, nrm * v[0]);
    atomicAdd(p + 1, nrm * v[1]);
    atomicAdd(p + 2, nrm * v[2]);
    atomicAdd(p + 3, nrm * v[3]);
}

// ---- self-loop + bias + relu for conv1 ----
__global__ __launch_bounds__(256) void sb_relu_kernel(float* __restrict__ h1,
                                                      const float* __restrict__ pre1,
                                                      const float* __restrict__ dinv,
                                                      const float* __restrict__ b1) {
    int gid = blockIdx.x * 256 + threadIdx.x;
    int v = gid >> 6;
    int c = (gid & 63) * 4;
    float d2 = dinv[v] * dinv[v];
    f32x4 h  = *(f32x4*)(h1 + (size_t)v * HID + c);
    f32x4 p  = *(const f32x4*)(pre1 + (size_t)v * HID + c);
    f32x4 bb = *(const f32x4*)(b1 + c);
#pragma unroll
    for (int i = 0; i < 4; ++i)
        h[i] = fmaxf(h[i] + d2 * p[i] + bb[i], 0.0f);
    *(f32x4*)(h1 + (size_t)v * HID + c) = h;
}

// ---- epilogue of conv2: finish mu/logstd, reparametrize, split z to bf16 hi/lo ----
__global__ __launch_bounds__(256) void z_kernel(const float* __restrict__ agg2,
                                                const float* __restrict__ pre2,
                                                const float* __restrict__ dinv,
                                                const float* __restrict__ bmu,
                                                const float* __restrict__ bls,
                                                const float* __restrict__ eps,
                                                float* __restrict__ out_mu,
                                                float* __restrict__ out_ls,
                                                u16* __restrict__ zhi,
                                                u16* __restrict__ zlo) {
    int gid = blockIdx.x * 256 + threadIdx.x;
    int v = gid >> 5;
    int c = (gid & 31) * 4;
    float d2 = dinv[v] * dinv[v];
    f32x4 am  = *(const f32x4*)(agg2 + (size_t)v * 256 + c);
    f32x4 als = *(const f32x4*)(agg2 + (size_t)v * 256 + 128 + c);
    f32x4 pm  = *(const f32x4*)(pre2 + (size_t)v * 256 + c);
    f32x4 pls = *(const f32x4*)(pre2 + (size_t)v * 256 + 128 + c);
    f32x4 ep  = *(const f32x4*)(eps + (size_t)v * 128 + c);
#pragma unroll
    for (int i = 0; i < 4; ++i) {
        float mu = am[i] + d2 * pm[i] + bmu[c + i];
        float ls = als[i] + d2 * pls[i] + bls[c + i];
        int idx = v * 128 + c + i;
        out_mu[idx] = mu;
        out_ls[idx] = ls;
        float z = ep[i] * __expf(ls) + mu;
        u16 hi = f2bf(z);
        float rem = z - bf2f(hi);
        zhi[idx] = hi;
        zlo[idx] = f2bf(rem);
    }
}

// ---- adj = sigmoid(z z^T) via split-bf16 MFMA (hi*hi + hi*lo + lo*hi) ----
// grid (64,64): 128x128 tile per block; 4 waves in 2x2, 64x64 per wave (4x4 MFMA tiles)
__global__ __launch_bounds__(256) void zzt_kernel(const u16* __restrict__ zhi,
                                                  const u16* __restrict__ zlo,
                                                  float* __restrict__ out) {
    const int lane = threadIdx.x & 63;
    const int wave = threadIdx.x >> 6;
    const int l16 = lane & 15, quad = lane >> 4;
    const int rowBase = blockIdx.y * 128 + (wave >> 1) * 64;
    const int colBase = blockIdx.x * 128 + (wave & 1) * 64;

    f32x4 acc[4][4] = {};

#pragma unroll
    for (int k0 = 0; k0 < LAT; k0 += 32) {
        const int kk = k0 + quad * 8;
        bf16x8 ah[4], al[4], bh[4], bl[4];
#pragma unroll
        for (int r = 0; r < 4; ++r) {
            int row = rowBase + r * 16 + l16;
            ah[r] = *(const bf16x8*)(zhi + (size_t)row * LAT + kk);
            al[r] = *(const bf16x8*)(zlo + (size_t)row * LAT + kk);
        }
#pragma unroll
        for (int c = 0; c < 4; ++c) {
            int row = colBase + c * 16 + l16;
            bh[c] = *(const bf16x8*)(zhi + (size_t)row * LAT + kk);
            bl[c] = *(const bf16x8*)(zlo + (size_t)row * LAT + kk);
        }
#pragma unroll
        for (int r = 0; r < 4; ++r)
#pragma unroll
            for (int c = 0; c < 4; ++c) {
                acc[r][c] = __builtin_amdgcn_mfma_f32_16x16x32_bf16(ah[r], bh[c], acc[r][c], 0, 0, 0);
                acc[r][c] = __builtin_amdgcn_mfma_f32_16x16x32_bf16(ah[r], bl[c], acc[r][c], 0, 0, 0);
                acc[r][c] = __builtin_amdgcn_mfma_f32_16x16x32_bf16(al[r], bh[c], acc[r][c], 0, 0, 0);
            }
    }

#pragma unroll
    for (int r = 0; r < 4; ++r)
#pragma unroll
        for (int c = 0; c < 4; ++c)
#pragma unroll
            for (int i = 0; i < 4; ++i) {
                int orow = rowBase + r * 16 + quad * 4 + i;
                int ocol = colBase + c * 16 + l16;
                float t = acc[r][c][i];
                out[(size_t)orow * N_NODES + ocol] = 1.0f / (1.0f + __expf(-t));
            }
}

extern "C" void kernel_launch(void* const* d_in, const int* in_sizes, int n_in,
                              void* d_out, int out_size, void* d_ws, size_t ws_size,
                              hipStream_t stream) {
    const float* x   = (const float*)d_in[0];
    const int*   ei  = (const int*)d_in[1];
    const float* eps = (const float*)d_in[2];
    const float* W1  = (const float*)d_in[3];
    const float* b1  = (const float*)d_in[4];
    const float* Wmu = (const float*)d_in[5];
    const float* bmu = (const float*)d_in[6];
    const float* Wls = (const float*)d_in[7];
    const float* bls = (const float*)d_in[8];
    const int* src = ei;
    const int* dst = ei + NEDGE;

    float* out = (float*)d_out;
    // temporaries parked inside the adj region of d_out (overwritten last by zzt)
    float* pre1 = out;                   // [8192,256]
    float* h1   = out + 2097152;         // [8192,256]
    float* pre2 = out + 4194304;         // [8192,256]  (cols 0..127 mu-pre, 128..255 ls-pre)
    float* agg2 = out + 6291456;         // [8192,256]
    float* out_mu = out + 67108864;      // [8192,128]
    float* out_ls = out + 68157440;      // [8192,128]

    float* dinv = (float*)d_ws;                                   // 32 KB
    u16* zhi = (u16*)((char*)d_ws + 32768);                       // 2 MB
    u16* zlo = (u16*)((char*)d_ws + 32768 + 2097152);             // 2 MB

    hipMemsetAsync(dinv, 0, 8192 * sizeof(float), stream);
    hipMemsetAsync(h1,   0, 2097152 * sizeof(float), stream);
    hipMemsetAsync(agg2, 0, 2097152 * sizeof(float), stream);

    deg_kernel<<<NEDGE / 256, 256, 0, stream>>>(dst, dinv);
    dinv_kernel<<<N_NODES / 256, 256, 0, stream>>>(dinv);

    // pre1 = x @ W1   [8192,512]x[512,256]
    gemm_f32<<<dim3(256 / 64, N_NODES / 64), 256, 0, stream>>>(x, W1, pre1, 512, 256, 256, 0);

    agg_kernel<<<NEDGE / 4, 256, 0, stream>>>(pre1, h1, src, dst, dinv);
    sb_relu_kernel<<<N_NODES * 64 / 256, 256, 0, stream>>>(h1, pre1, dinv, b1);

    // pre2[:,0:128] = h1@Wmu ; pre2[:,128:256] = h1@Wls
    gemm_f32<<<dim3(2, N_NODES / 64), 256, 0, stream>>>(h1, Wmu, pre2, 256, 128, 256, 0);
    gemm_f32<<<dim3(2, N_NODES / 64), 256, 0, stream>>>(h1, Wls, pre2, 256, 128, 256, 128);

    agg_kernel<<<NEDGE / 4, 256, 0, stream>>>(pre2, agg2, src, dst, dinv);

    z_kernel<<<N_NODES * 32 / 256, 256, 0, stream>>>(agg2, pre2, dinv, bmu, bls, eps,
                                                     out_mu, out_ls, zhi, zlo);

    zzt_kernel<<<dim3(64, 64), 256, 0, stream>>>(zhi, zlo, out);
}

// Round 2
// 543.309 us; speedup vs baseline: 4.0985x; 4.0985x over previous
//
#include <hip/hip_runtime.h>

#define N_NODES 8192
#define IN_DIM  512
#define HID     256
#define LAT     128
#define NEDGE   262144

typedef __attribute__((ext_vector_type(8))) short  bf16x8;
typedef __attribute__((ext_vector_type(4))) float  f32x4;
typedef unsigned short u16;

// ---- bf16 helpers (manual, RNE) ----
static __device__ inline u16 f2bf(float f) {
    unsigned u = __float_as_uint(f);
    unsigned r = (u + 0x7fffu + ((u >> 16) & 1u)) >> 16;
    return (u16)r;
}
static __device__ inline float bf2f(u16 s) {
    return __uint_as_float(((unsigned)s) << 16);
}

// ================= CSR build =================

__global__ __launch_bounds__(256) void count_kernel(const int* __restrict__ dst,
                                                    int* __restrict__ cnt) {
    int e = blockIdx.x * 256 + threadIdx.x;
    atomicAdd(&cnt[dst[e]], 1);
}

__global__ __launch_bounds__(256) void dinv_kernel(const int* __restrict__ cnt,
                                                   float* __restrict__ dinv) {
    int v = blockIdx.x * 256 + threadIdx.x;
    dinv[v] = rsqrtf((float)cnt[v] + 1.0f);   // +1 self-loop
}

// single-block exclusive scan of 8192 counts -> rowptr[8193], cursor copy
__global__ __launch_bounds__(256) void scan_kernel(const int* __restrict__ cnt,
                                                   int* __restrict__ rowptr,
                                                   int* __restrict__ cursor) {
    __shared__ int part[256];
    const int t = threadIdx.x;
    const int base = t * 32;
    int local[32];
    int s = 0;
#pragma unroll
    for (int i = 0; i < 32; ++i) { local[i] = s; s += cnt[base + i]; }
    part[t] = s;
    __syncthreads();
    for (int off = 1; off < 256; off <<= 1) {
        int v = 0;
        if (t >= off) v = part[t - off];
        __syncthreads();
        if (t >= off) part[t] += v;
        __syncthreads();
    }
    int pre = (t == 0) ? 0 : part[t - 1];
#pragma unroll
    for (int i = 0; i < 32; ++i) {
        int r = pre + local[i];
        rowptr[base + i] = r;
        cursor[base + i] = r;
    }
    if (t == 255) rowptr[8192] = part[255];
}

__global__ __launch_bounds__(256) void fill_kernel(const int* __restrict__ src,
                                                   const int* __restrict__ dst,
                                                   int* __restrict__ cursor,
                                                   int* __restrict__ ebuf) {
    int e = blockIdx.x * 256 + threadIdx.x;
    int pos = atomicAdd(&cursor[dst[e]], 1);
    ebuf[pos] = src[e];
}

// ================= dense GEMM (fp32 vector) =================
// C[., coff + colBase...] = A[M,K] @ B[K,ldb] ; 64x64 tile, BK=16, 4x4/thread
__global__ __launch_bounds__(256) void gemm_f32(const float* __restrict__ A,
                                                const float* __restrict__ B,
                                                float* __restrict__ C,
                                                int Ktot, int ldb, int ldc, int coff) {
    __shared__ float As[16][68];
    __shared__ float Bs[16][64];
    const int tid = threadIdx.x;
    const int tx = tid & 15, ty = tid >> 4;
    const int rowBase = blockIdx.y * 64, colBase = blockIdx.x * 64;

    float acc[4][4] = {};
    const int am = rowBase + (tid >> 2);
    const int ak = (tid & 3) * 4;
    const int bk = tid >> 4;
    const int bn = colBase + (tid & 15) * 4;

    for (int k0 = 0; k0 < Ktot; k0 += 16) {
        f32x4 av = *(const f32x4*)(A + (size_t)am * Ktot + k0 + ak);
        f32x4 bv = *(const f32x4*)(B + (size_t)(k0 + bk) * ldb + bn);
#pragma unroll
        for (int j = 0; j < 4; ++j) As[ak + j][tid >> 2] = av[j];
        *(f32x4*)&Bs[bk][(tid & 15) * 4] = bv;
        __syncthreads();
#pragma unroll
        for (int kk = 0; kk < 16; ++kk) {
            f32x4 a = *(const f32x4*)&As[kk][ty * 4];
            f32x4 b = *(const f32x4*)&Bs[kk][tx * 4];
#pragma unroll
            for (int i = 0; i < 4; ++i)
#pragma unroll
                for (int j = 0; j < 4; ++j)
                    acc[i][j] += a[i] * b[j];
        }
        __syncthreads();
    }
#pragma unroll
    for (int i = 0; i < 4; ++i) {
        int r = rowBase + ty * 4 + i;
        f32x4 v = { acc[i][0], acc[i][1], acc[i][2], acc[i][3] };
        *(f32x4*)(C + (size_t)r * ldc + coff + colBase + tx * 4) = v;
    }
}

// ================= CSR gather aggregation =================
// conv1: h1[v] = relu( sum_s nrm*pre1[s] + d2*pre1[v] + b1 ), one wave per node
__global__ __launch_bounds__(256) void gather1_kernel(const float* __restrict__ pre1,
                                                      float* __restrict__ h1,
                                                      const int* __restrict__ rowptr,
                                                      const int* __restrict__ ebuf,
                                                      const float* __restrict__ dinv,
                                                      const float* __restrict__ b1) {
    const int wave = threadIdx.x >> 6, lane = threadIdx.x & 63;
    const int v = blockIdx.x * 4 + wave;
    const int c = lane * 4;
    const float dv = dinv[v];
    f32x4 acc = *(const f32x4*)(pre1 + (size_t)v * HID + c);
    acc *= dv * dv;
    int i = rowptr[v], end = rowptr[v + 1];
    for (; i + 1 < end; i += 2) {
        int s0 = ebuf[i], s1 = ebuf[i + 1];
        float n0 = dv * dinv[s0], n1 = dv * dinv[s1];
        f32x4 h0 = *(const f32x4*)(pre1 + (size_t)s0 * HID + c);
        f32x4 h1v = *(const f32x4*)(pre1 + (size_t)s1 * HID + c);
#pragma unroll
        for (int j = 0; j < 4; ++j) acc[j] += n0 * h0[j] + n1 * h1v[j];
    }
    if (i < end) {
        int s0 = ebuf[i];
        float n0 = dv * dinv[s0];
        f32x4 h0 = *(const f32x4*)(pre1 + (size_t)s0 * HID + c);
#pragma unroll
        for (int j = 0; j < 4; ++j) acc[j] += n0 * h0[j];
    }
    f32x4 bb = *(const f32x4*)(b1 + c);
#pragma unroll
    for (int j = 0; j < 4; ++j) acc[j] = fmaxf(acc[j] + bb[j], 0.0f);
    *(f32x4*)(h1 + (size_t)v * HID + c) = acc;
}

// conv2 + reparametrize: pre2 cols 0..127 = mu-pre, 128..255 = ls-pre.
// Aggregate 256 cols per node, then lanes<32 hold mu, lanes>=32 hold ls.
__global__ __launch_bounds__(256) void gather2_kernel(const float* __restrict__ pre2,
                                                      const int* __restrict__ rowptr,
                                                      const int* __restrict__ ebuf,
                                                      const float* __restrict__ dinv,
                                                      const float* __restrict__ bmu,
                                                      const float* __restrict__ bls,
                                                      const float* __restrict__ eps,
                                                      float* __restrict__ out_mu,
                                                      float* __restrict__ out_ls,
                                                      u16* __restrict__ zhi,
                                                      u16* __restrict__ zlo) {
    const int wave = threadIdx.x >> 6, lane = threadIdx.x & 63;
    const int v = blockIdx.x * 4 + wave;
    const int c = lane * 4;
    const float dv = dinv[v];
    f32x4 acc = *(const f32x4*)(pre2 + (size_t)v * HID + c);
    acc *= dv * dv;
    int i = rowptr[v], end = rowptr[v + 1];
    for (; i + 1 < end; i += 2) {
        int s0 = ebuf[i], s1 = ebuf[i + 1];
        float n0 = dv * dinv[s0], n1 = dv * dinv[s1];
        f32x4 h0 = *(const f32x4*)(pre2 + (size_t)s0 * HID + c);
        f32x4 h1v = *(const f32x4*)(pre2 + (size_t)s1 * HID + c);
#pragma unroll
        for (int j = 0; j < 4; ++j) acc[j] += n0 * h0[j] + n1 * h1v[j];
    }
    if (i < end) {
        int s0 = ebuf[i];
        float n0 = dv * dinv[s0];
        f32x4 h0 = *(const f32x4*)(pre2 + (size_t)s0 * HID + c);
#pragma unroll
        for (int j = 0; j < 4; ++j) acc[j] += n0 * h0[j];
    }
    // bias
    const float* bias = (lane < 32) ? (bmu + c) : (bls + (c - 128));
    f32x4 bb = *(const f32x4*)bias;
#pragma unroll
    for (int j = 0; j < 4; ++j) acc[j] += bb[j];

    // pair mu (lane<32) with ls (lane+32)
    f32x4 other;
#pragma unroll
    for (int j = 0; j < 4; ++j) other[j] = __shfl(acc[j], (lane + 32) & 63, 64);

    if (lane < 32) {
        int idx = v * LAT + c;
        f32x4 ep = *(const f32x4*)(eps + idx);
        *(f32x4*)(out_mu + idx) = acc;
#pragma unroll
        for (int j = 0; j < 4; ++j) {
            float z = ep[j] * __expf(other[j]) + acc[j];
            u16 hi = f2bf(z);
            zhi[idx + j] = hi;
            zlo[idx + j] = f2bf(z - bf2f(hi));
        }
    } else {
        int idx = v * LAT + (c - 128);
        *(f32x4*)(out_ls + idx) = acc;
    }
}

// ================= adj = sigmoid(z z^T), split-bf16 MFMA =================
__global__ __launch_bounds__(256) void zzt_kernel(const u16* __restrict__ zhi,
                                                  const u16* __restrict__ zlo,
                                                  float* __restrict__ out) {
    const int lane = threadIdx.x & 63;
    const int wave = threadIdx.x >> 6;
    const int l16 = lane & 15, quad = lane >> 4;
    const int rowBase = blockIdx.y * 128 + (wave >> 1) * 64;
    const int colBase = blockIdx.x * 128 + (wave & 1) * 64;

    f32x4 acc[4][4] = {};

#pragma unroll
    for (int k0 = 0; k0 < LAT; k0 += 32) {
        const int kk = k0 + quad * 8;
        bf16x8 ah[4], al[4], bh[4], bl[4];
#pragma unroll
        for (int r = 0; r < 4; ++r) {
            int row = rowBase + r * 16 + l16;
            ah[r] = *(const bf16x8*)(zhi + (size_t)row * LAT + kk);
            al[r] = *(const bf16x8*)(zlo + (size_t)row * LAT + kk);
        }
#pragma unroll
        for (int c = 0; c < 4; ++c) {
            int row = colBase + c * 16 + l16;
            bh[c] = *(const bf16x8*)(zhi + (size_t)row * LAT + kk);
            bl[c] = *(const bf16x8*)(zlo + (size_t)row * LAT + kk);
        }
#pragma unroll
        for (int r = 0; r < 4; ++r)
#pragma unroll
            for (int c = 0; c < 4; ++c) {
                acc[r][c] = __builtin_amdgcn_mfma_f32_16x16x32_bf16(ah[r], bh[c], acc[r][c], 0, 0, 0);
                acc[r][c] = __builtin_amdgcn_mfma_f32_16x16x32_bf16(ah[r], bl[c], acc[r][c], 0, 0, 0);
                acc[r][c] = __builtin_amdgcn_mfma_f32_16x16x32_bf16(al[r], bh[c], acc[r][c], 0, 0, 0);
            }
    }

#pragma unroll
    for (int r = 0; r < 4; ++r)
#pragma unroll
        for (int c = 0; c < 4; ++c)
#pragma unroll
            for (int i = 0; i < 4; ++i) {
                int orow = rowBase + r * 16 + quad * 4 + i;
                int ocol = colBase + c * 16 + l16;
                float t = acc[r][c][i];
                out[(size_t)orow * N_NODES + ocol] = 1.0f / (1.0f + __expf(-t));
            }
}

extern "C" void kernel_launch(void* const* d_in, const int* in_sizes, int n_in,
                              void* d_out, int out_size, void* d_ws, size_t ws_size,
                              hipStream_t stream) {
    const float* x   = (const float*)d_in[0];
    const int*   ei  = (const int*)d_in[1];
    const float* eps = (const float*)d_in[2];
    const float* W1  = (const float*)d_in[3];
    const float* b1  = (const float*)d_in[4];
    const float* Wmu = (const float*)d_in[5];
    const float* bmu = (const float*)d_in[6];
    const float* Wls = (const float*)d_in[7];
    const float* bls = (const float*)d_in[8];
    const int* src = ei;
    const int* dst = ei + NEDGE;

    float* out = (float*)d_out;
    // temporaries parked inside adj region of d_out (zzt overwrites last)
    float* pre1 = out;                    // [8192,256]
    float* h1   = out + 2097152;          // [8192,256]
    float* pre2 = out + 4194304;          // [8192,256] cols 0..127 mu-pre, 128..255 ls-pre
    int*   ibase  = (int*)(out + 6291456);
    int*   cnt    = ibase;                // 8192
    int*   rowptr = ibase + 8192;         // 8193
    int*   cursor = ibase + 16385;        // 8192
    int*   ebuf   = ibase + 24577;        // 262144
    float* out_mu = out + 67108864;       // [8192,128]
    float* out_ls = out + 68157440;       // [8192,128]

    float* dinv = (float*)d_ws;                               // 32 KB
    u16* zhi = (u16*)((char*)d_ws + 32768);                   // 2 MB
    u16* zlo = (u16*)((char*)d_ws + 32768 + 2097152);         // 2 MB

    hipMemsetAsync(cnt, 0, 8192 * sizeof(int), stream);

    count_kernel<<<NEDGE / 256, 256, 0, stream>>>(dst, cnt);
    dinv_kernel<<<N_NODES / 256, 256, 0, stream>>>(cnt, dinv);
    scan_kernel<<<1, 256, 0, stream>>>(cnt, rowptr, cursor);
    fill_kernel<<<NEDGE / 256, 256, 0, stream>>>(src, dst, cursor, ebuf);

    // pre1 = x @ W1
    gemm_f32<<<dim3(256 / 64, N_NODES / 64), 256, 0, stream>>>(x, W1, pre1, 512, 256, 256, 0);
    gather1_kernel<<<N_NODES / 4, 256, 0, stream>>>(pre1, h1, rowptr, ebuf, dinv, b1);

    // pre2[:,0:128] = h1@Wmu ; pre2[:,128:256] = h1@Wls
    gemm_f32<<<dim3(2, N_NODES / 64), 256, 0, stream>>>(h1, Wmu, pre2, 256, 128, 256, 0);
    gemm_f32<<<dim3(2, N_NODES / 64), 256, 0, stream>>>(h1, Wls, pre2, 256, 128, 256, 128);

    gather2_kernel<<<N_NODES / 4, 256, 0, stream>>>(pre2, rowptr, ebuf, dinv, bmu, bls, eps,
                                                    out_mu, out_ls, zhi, zlo);

    zzt_kernel<<<dim3(64, 64), 256, 0, stream>>>(zhi, zlo, out);
}